// Round 3
// baseline (2069.691 us; speedup 1.0000x reference)
//
#include <hip/hip_runtime.h>
#include <stdint.h>

// IndexFlatIP top-k: sims = Q[512,512] @ X[262144,512]^T, per-row top-10
// indices (desc, ties -> lower index). Output int32 [512,10].
//
// Round 3: pre-split fp32 -> f16 hi/lo planes in d_ws (split8 kernel), then
// p1 = m97-structure MFMA GEMM (global_load_lds staging, no in-loop VALU
// conversion) with fused per-row top-10. p2 = exact rank merge (unchanged,
// verified). Numerics identical to round-2 (absmax 0): sim = Qh.Xh +
// (Qh.Xl + Ql.Xh)/2048, lo scaled by 2^11 at split time.
#define B_Q   512
#define N_IDX 262144
#define D_DIM 512
#define TOPK  10

constexpr int BM = 128;
constexpr int BN = 128;
constexpr int BK = 32;
constexpr int NCHUNK = 128;          // global N-chunks (candidate lists)
constexpr int NR = N_IDX / NCHUNK;   // 2048 cols per chunk
constexpr int NTILES = NR / BN;      // 16
constexpr int KTILES = D_DIM / BK;   // 16

typedef _Float16 half8 __attribute__((ext_vector_type(8)));
typedef float    f32x4 __attribute__((ext_vector_type(4)));

// ---------------------------------------------------------------- staging --
// Async 16B global->LDS. LDS dest is wave-uniform; HW adds lane*16 (m104).
__device__ __forceinline__ void stage16(const void* g, char* lds_uniform, int lane)
{
#if defined(__has_builtin) && __has_builtin(__builtin_amdgcn_global_load_lds)
    __builtin_amdgcn_global_load_lds(
        (const __attribute__((address_space(1))) void*)g,
        (__attribute__((address_space(3))) void*)lds_uniform, 16, 0, 0);
    (void)lane;
#else
    *(uint4*)(lds_uniform + lane * 16) = *(const uint4*)g;  // sync fallback
#endif
}

// ------------------------------------------------------------------ split --
// fp32 -> (f16 hi, f16 lo*2^11) planes, 8 elems per thread.
__global__ __launch_bounds__(256)
void split8(const float* __restrict__ src, _Float16* __restrict__ h,
            _Float16* __restrict__ l, int n8)
{
    const int i = blockIdx.x * 256 + threadIdx.x;
    if (i >= n8) return;
    const float4 p0 = reinterpret_cast<const float4*>(src)[i * 2];
    const float4 p1 = reinterpret_cast<const float4*>(src)[i * 2 + 1];
    const float x[8] = {p0.x, p0.y, p0.z, p0.w, p1.x, p1.y, p1.z, p1.w};
    half8 hh, ll;
#pragma unroll
    for (int e = 0; e < 8; ++e) {
        const _Float16 t = (_Float16)x[e];
        hh[e] = t;
        ll[e] = (_Float16)((x[e] - (float)t) * 2048.0f);
    }
    reinterpret_cast<half8*>(h)[i] = hh;
    reinterpret_cast<half8*>(l)[i] = ll;
}

// --------------------------------------------------------------------- p1 --
// Grid (chunksPerSlice, 4), block 256 (4 waves, wave tile 64x64, 4x4 frags).
// LDS 32 KB: 4 regions x 8 KB (Ah, Al, Bh, Bl), granule(slot,row) -> 16 B at
// (slot*128+row)*16. Staged via global_load_lds (linear in lane order).
// Epilogue overlays 128x64 fp32 scratch (XOR swizzle) on same LDS.
__global__ __launch_bounds__(256, 2)
void faiss_p1(const _Float16* __restrict__ Qh, const _Float16* __restrict__ Ql,
              const _Float16* __restrict__ Xh, const _Float16* __restrict__ Xl,
              float* __restrict__ cand_v, int* __restrict__ cand_i, int chunk0)
{
    __shared__ __align__(16) char smem[32768];
    _Float16* AhB = (_Float16*)(smem);
    _Float16* AlB = (_Float16*)(smem + 8192);
    _Float16* BhB = (_Float16*)(smem + 16384);
    _Float16* BlB = (_Float16*)(smem + 24576);
    float*    Cs  = (float*)(smem);

    const int tid  = threadIdx.x;
    const int lane = tid & 63;
    const int wm   = (tid >> 6) >> 1;      // 0..1
    const int wn   = (tid >> 6) & 1;       // 0..1
    const int row0 = blockIdx.y * BM;
    const int chunk = chunk0 + blockIdx.x;     // global chunk id (candidates)
    const int lcol0 = blockIdx.x * NR;         // slice-local col base (Xh/Xl)

    // staging granules: gi = tid + 256*i (i=0,1) in each region.
    // granule gi: row = gi&127, slot = gi>>7; element offset row*D + slot*8.
    const int gA0r = tid & 127,         gA0s = tid >> 7;
    const int gA1r = (tid + 256) & 127, gA1s = (tid + 256) >> 7;
    // wave-uniform LDS byte offsets within a region
    const int dst0 = ((tid & 0xC0)) * 16;          // i=0: granules w*64..
    const int dst1 = ((tid & 0xC0) + 256) * 16;    // i=1

    // fragment element offsets within a region (8 f16 per read)
    int a_off[4], b_off[4];
#pragma unroll
    for (int i = 0; i < 4; ++i) {
        a_off[i] = ((lane >> 4) * 128 + wm * 64 + i * 16 + (lane & 15)) * 8;
        b_off[i] = ((lane >> 4) * 128 + wn * 64 + i * 16 + (lane & 15)) * 8;
    }

    float topv[TOPK]; int topi[TOPK];
#pragma unroll
    for (int j = 0; j < TOPK; ++j) { topv[j] = -3.0e38f; topi[j] = 0; }

    for (int nt = 0; nt < NTILES; ++nt) {
        const int col0g = chunk * NR + nt * BN;    // global (candidate ids)
        const int col0l = lcol0 + nt * BN;         // slice-local (memory)

        // element offsets at kt=0 for this nt
        int a0 = (row0 + gA0r) * D_DIM + gA0s * 8;
        int a1 = (row0 + gA1r) * D_DIM + gA1s * 8;
        int b0 = (col0l + gA0r) * D_DIM + gA0s * 8;
        int b1 = (col0l + gA1r) * D_DIM + gA1s * 8;

        f32x4 acc[4][4], acc2[4][4];
#pragma unroll
        for (int i = 0; i < 4; ++i)
#pragma unroll
            for (int j = 0; j < 4; ++j) {
                acc[i][j] = (f32x4)0.0f; acc2[i][j] = (f32x4)0.0f;
            }

        for (int kt = 0; kt < KTILES; ++kt) {
            stage16(Qh + a0, smem         + dst0, lane);
            stage16(Qh + a1, smem         + dst1, lane);
            stage16(Ql + a0, smem + 8192  + dst0, lane);
            stage16(Ql + a1, smem + 8192  + dst1, lane);
            stage16(Xh + b0, smem + 16384 + dst0, lane);
            stage16(Xh + b1, smem + 16384 + dst1, lane);
            stage16(Xl + b0, smem + 24576 + dst0, lane);
            stage16(Xl + b1, smem + 24576 + dst1, lane);
            a0 += BK; a1 += BK; b0 += BK; b1 += BK;
            __syncthreads();

            half8 ah[4], al[4];
#pragma unroll
            for (int mi = 0; mi < 4; ++mi) {
                ah[mi] = *reinterpret_cast<half8*>(&AhB[a_off[mi]]);
                al[mi] = *reinterpret_cast<half8*>(&AlB[a_off[mi]]);
            }
#pragma unroll
            for (int ni = 0; ni < 4; ++ni) {
                const half8 bh = *reinterpret_cast<half8*>(&BhB[b_off[ni]]);
                const half8 bl = *reinterpret_cast<half8*>(&BlB[b_off[ni]]);
#pragma unroll
                for (int mi = 0; mi < 4; ++mi) {
                    acc [mi][ni] = __builtin_amdgcn_mfma_f32_16x16x32_f16(ah[mi], bh, acc [mi][ni], 0, 0, 0);
                    acc2[mi][ni] = __builtin_amdgcn_mfma_f32_16x16x32_f16(al[mi], bh, acc2[mi][ni], 0, 0, 0);
                    acc2[mi][ni] = __builtin_amdgcn_mfma_f32_16x16x32_f16(ah[mi], bl, acc2[mi][ni], 0, 0, 0);
                }
            }
            __syncthreads();
        }

        // epilogue: dump (XOR-swizzled) + per-row scan. C/D: col=lane&15,
        // row=(lane>>4)*4+reg (m89). Identical to verified round-2 code.
#pragma unroll
        for (int h = 0; h < 2; ++h) {
            if (wn == h) {
#pragma unroll
                for (int mi = 0; mi < 4; ++mi)
#pragma unroll
                    for (int ni = 0; ni < 4; ++ni)
#pragma unroll
                        for (int r = 0; r < 4; ++r) {
                            const int row = wm * 64 + mi * 16 + (lane >> 4) * 4 + r;
                            const int c   = ni * 16 + (lane & 15);
                            Cs[row * 64 + (c ^ (row & 31))] =
                                acc[mi][ni][r] + acc2[mi][ni][r] * (1.0f / 2048.0f);
                        }
            }
            __syncthreads();
            if (tid < BM) {
                const int r = tid;
                const int base = col0g + h * 64;
                for (int c = 0; c < 64; ++c) {
                    const float v  = Cs[r * 64 + (c ^ (r & 31))];
                    const int   id = base + c;
                    if (v > topv[TOPK - 1] ||
                        (v == topv[TOPK - 1] && id < topi[TOPK - 1])) {
                        topv[TOPK - 1] = v; topi[TOPK - 1] = id;
#pragma unroll
                        for (int j = TOPK - 1; j > 0; --j) {
                            const bool gt = topv[j] > topv[j - 1] ||
                                (topv[j] == topv[j - 1] && topi[j] < topi[j - 1]);
                            if (gt) {
                                const float tv = topv[j]; topv[j] = topv[j - 1]; topv[j - 1] = tv;
                                const int   ti = topi[j]; topi[j] = topi[j - 1]; topi[j - 1] = ti;
                            }
                        }
                    }
                }
            }
            __syncthreads();
        }
    }

    if (tid < BM) {
        const size_t base = ((size_t)(row0 + tid) * NCHUNK + chunk) * TOPK;
#pragma unroll
        for (int j = 0; j < TOPK; ++j) {
            cand_v[base + j] = topv[j];
            cand_i[base + j] = topi[j];
        }
    }
}

constexpr int NCAND = NCHUNK * TOPK;   // 1280 per row

// --------------------------------------------------------------------- p2 --
__global__ __launch_bounds__(256)
void faiss_p2_merge(const float* __restrict__ cand_v, const int* __restrict__ cand_i,
                    int* __restrict__ out)
{
    __shared__ float vs[NCAND];
    __shared__ int   is[NCAND];
    const int row = blockIdx.x;
    const int tid = threadIdx.x;

    for (int i = tid; i < NCAND; i += 256) {
        vs[i] = cand_v[(size_t)row * NCAND + i];
        is[i] = cand_i[(size_t)row * NCAND + i];
    }
    __syncthreads();

    for (int c = tid; c < NCAND; c += 256) {
        const float v  = vs[c];
        const int   id = is[c];
        int rank = 0;
        for (int j = 0; j < NCAND; ++j) {
            const float vj = vs[j];
            rank += (vj > v) || (vj == v && is[j] < id);
        }
        if (rank < TOPK) out[row * TOPK + rank] = id;
    }
}

// ----------------------------------------------------------------- launch --
extern "C" void kernel_launch(void* const* d_in, const int* in_sizes, int n_in,
                              void* d_out, int out_size, void* d_ws, size_t ws_size,
                              hipStream_t stream)
{
    (void)in_sizes; (void)n_in; (void)out_size;
    const float* Q = (const float*)d_in[0];
    const float* X = (const float*)d_in[1];
    int* out = (int*)d_out;

    // workspace layout
    char* ws = (char*)d_ws;
    float*    cand_v = (float*)ws;                          // 2.62 MB
    int*      cand_i = (int*)(ws + 2621440);                // 2.62 MB
    _Float16* Qh     = (_Float16*)(ws + 5242880);           // 512 KB
    _Float16* Ql     = (_Float16*)(ws + 5767168);           // 512 KB
    _Float16* Xh;    // slice planes, sized below
    _Float16* Xl;
    const size_t fixed = 6291456;

    // pick slice count P: slice planes need 2*(N/P)*512*2 bytes
    int P = 1;
    while (P < 32) {
        const size_t need = (size_t)536870912 / P;
        if (fixed + need <= ws_size) break;
        P *= 2;
    }
    const int rowsP   = N_IDX / P;
    const int chunksP = NCHUNK / P;
    Xh = (_Float16*)(ws + fixed);
    Xl = Xh + (size_t)rowsP * D_DIM;

    // split Q once (1 MB)
    split8<<<dim3((B_Q * D_DIM / 8 + 255) / 256), dim3(256), 0, stream>>>(
        Q, Qh, Ql, B_Q * D_DIM / 8);

    const int n8x = rowsP * D_DIM / 8;
    for (int p = 0; p < P; ++p) {
        split8<<<dim3((n8x + 255) / 256), dim3(256), 0, stream>>>(
            X + (size_t)p * rowsP * D_DIM, Xh, Xl, n8x);
        faiss_p1<<<dim3(chunksP, B_Q / BM), dim3(256), 0, stream>>>(
            Qh, Ql, Xh, Xl, cand_v, cand_i, p * chunksP);
    }
    faiss_p2_merge<<<dim3(B_Q), dim3(256), 0, stream>>>(cand_v, cand_i, out);
}

// Round 5
// 510.146 us; speedup vs baseline: 4.0571x; 4.0571x over previous
//
#include <hip/hip_runtime.h>
#include <stdint.h>

// IndexFlatIP top-k: sims = Q[512,512] @ X[262144,512]^T, per-row top-10
// indices (desc, ties -> lower index). Output int32 [512,10].
//
// Round 5 (= round-4 design, compile-fixed: cvt_pkrtz results moved via
// __builtin_bit_cast to u32 words):
//  qprep: Q fp32 -> f16 (RTZ) in GEMM-granule order (Qsw), 1 MB, once.
//  p1   : f16 single-plane MFMA GEMM, X fp32 converted in-register
//         (cvt_pkrtz) during staging. T3/T4-min pipeline: raw s_barrier +
//         counted vmcnt(1), 2-deep reg prefetch of X, global_load_lds for
//         Qsw, LDS double-buffer. Fused per-row top-6 per 1024-col chunk.
//  p2   : pivot-filtered candidate pool (provable superset of true top-24),
//         exact fp32 rescore from original Q,X, deterministic rank -> out.
#define B_Q   512
#define N_IDX 262144
#define D_DIM 512
#define TOPK  10
#define CAND  6

constexpr int BM = 256, BN = 64, BK = 32;
constexpr int CHUNKS = 256;          // candidate chunks (= N-slabs of 1024)
constexpr int NR = N_IDX / CHUNKS;   // 1024 cols per chunk
constexpr int NT = NR / BN;          // 16
constexpr int KT = D_DIM / BK;       // 16
constexpr int ITERS = NT * KT;       // 256
constexpr int NCAND = CHUNKS * CAND; // 1536 per row

typedef _Float16 half8  __attribute__((ext_vector_type(8)));
typedef float    f32x4  __attribute__((ext_vector_type(4)));

__device__ __forceinline__ unsigned int pk16(float a, float b)
{
    return __builtin_bit_cast(unsigned int, __builtin_amdgcn_cvt_pkrtz(a, b));
}

__device__ __forceinline__ void glds16(const void* g, char* lds)
{
    __builtin_amdgcn_global_load_lds(
        (const __attribute__((address_space(1))) void*)g,
        (__attribute__((address_space(3))) void*)lds, 16, 0, 0);
}

// ------------------------------------------------------------------ qprep --
// Q fp32 -> f16 RTZ, written in p1's LDS-granule order:
// granule g = (qt*16+kt)*1024 + slot*256 + row holds 8 f16 (16 B).
__global__ __launch_bounds__(256)
void qprep(const float* __restrict__ Q, _Float16* __restrict__ Qsw)
{
    const int n = blockIdx.x * 256 + threadIdx.x;   // 32768 granules
    const float4 p0 = reinterpret_cast<const float4*>(Q)[n * 2];
    const float4 p1 = reinterpret_cast<const float4*>(Q)[n * 2 + 1];
    uint4 u;
    u.x = pk16(p0.x, p0.y);
    u.y = pk16(p0.z, p0.w);
    u.z = pk16(p1.x, p1.y);
    u.w = pk16(p1.z, p1.w);
    // n = (qt*256+row)*64 + kt*4 + slot   (coalesced source)
    const int kslot = n & 63, rowg = n >> 6;
    const int kt = kslot >> 2, slot = kslot & 3;
    const int qt = rowg >> 8, row = rowg & 255;
    reinterpret_cast<uint4*>(Qsw)[(qt * 16 + kt) * 1024 + slot * 256 + row] = u;
}

// --------------------------------------------------------------------- p1 --
// Grid 512 (bc = bx>>1, qt = bx&1), block 512 = 8 waves (4M x 2N),
// wave tile 64x32, acc 8 x f32x4 = 32 VGPR.
// LDS 56 KB: Abuf[2] 16K @0/@16K, Bbuf[2] 4K @32K/@36K, Cs 16K @40K.
__global__ __launch_bounds__(512, 4)
void faiss_p1(const _Float16* __restrict__ Qsw, const float* __restrict__ X,
              float* __restrict__ cand_v, int* __restrict__ cand_i)
{
    __shared__ __align__(16) char smem[57344];
    float* Cs = (float*)(smem + 40960);

    const int tid  = threadIdx.x;
    const int lane = tid & 63;
    const int w    = tid >> 6;
    const int wm   = w >> 1;       // 0..3 (M quarter, 64 rows)
    const int wn   = w & 1;        // 0..1 (N half, 32 cols)
    const int bc   = blockIdx.x >> 1;
    const int qt   = blockIdx.x & 1;
    const int row0 = qt * 256;

    // A staging: wave w stages granules w*128 + {0..63, 64..127} per K-step.
    const _Float16* Aglob = Qsw + (size_t)qt * 131072;   // 16 kt * 1024 gran * 8
    const int aG0 = w * 128 + lane, aG1 = aG0 + 64;      // per-lane src granule
    const int aD0 = w * 2048, aD1 = aD0 + 1024;          // wave-uniform dst bytes

    // B staging: thread -> (row = tid>>3, quad = tid&7), 4 fp32 -> 4 f16.
    const int brow = tid >> 3, bq = tid & 7;
    const float* Xb = X + (size_t)(bc * NR + brow) * D_DIM + bq * 4;
    const int bD = ((bq >> 1) * 64 + brow) * 16 + (bq & 1) * 8;

    // fragment LDS byte offsets
    int a_off[4], b_off[2];
#pragma unroll
    for (int mi = 0; mi < 4; ++mi)
        a_off[mi] = ((lane >> 4) * 256 + wm * 64 + mi * 16 + (lane & 15)) * 16;
#pragma unroll
    for (int ni = 0; ni < 2; ++ni)
        b_off[ni] = ((lane >> 4) * 64 + wn * 32 + ni * 16 + (lane & 15)) * 16;

    float topv[CAND]; int topi[CAND];
#pragma unroll
    for (int j = 0; j < CAND; ++j) { topv[j] = -3.0e38f; topi[j] = 0; }

    f32x4 acc[4][2];
#pragma unroll
    for (int mi = 0; mi < 4; ++mi) { acc[mi][0] = (f32x4)0.0f; acc[mi][1] = (f32x4)0.0f; }

    // prologue: A(0) -> Abuf0; B(0), B(1) -> regs (queue order pinned below)
    float4 bE, bO;
    glds16(Aglob + (size_t)aG0 * 8, smem + aD0);
    glds16(Aglob + (size_t)aG1 * 8, smem + aD1);
    __builtin_amdgcn_sched_barrier(0);
    bE = *(const float4*)(Xb);          // j=0: nt=0, ke=0
    bO = *(const float4*)(Xb + 32);     // j=1: nt=0, ke=32
    __builtin_amdgcn_sched_barrier(0);

    auto step = [&](int j, float4& bset) {
        // wait: A(j) + B(j) complete; keep B(j+1) in flight (counted, T4)
        if (j == 0 || j == ITERS - 1)
            asm volatile("s_waitcnt vmcnt(0)" ::: "memory");
        else
            asm volatile("s_waitcnt vmcnt(1)" ::: "memory");
        // convert + ds_write B(j) into Bbuf[j&1]
        {
            uint2 u;
            u.x = pk16(bset.x, bset.y);
            u.y = pk16(bset.z, bset.w);
            *(uint2*)(smem + 32768 + (j & 1) * 4096 + bD) = u;
        }
        asm volatile("s_waitcnt lgkmcnt(0)" ::: "memory");
        __builtin_amdgcn_s_barrier();
        // prefetch A(j+1) -> Abuf[(j+1)&1]   (safe: compute(j-1) LDS reads
        // were drained by the lgkmcnt(0) before this barrier)
        if (j + 1 < ITERS) {
            const int kn = ((j + 1) & 15) * 1024;
            char* dst = smem + ((j + 1) & 1) * 16384;
            glds16(Aglob + (size_t)(kn + aG0) * 8, dst + aD0);
            glds16(Aglob + (size_t)(kn + aG1) * 8, dst + aD1);
        }
        __builtin_amdgcn_sched_barrier(0);
        // prefetch B(j+2) -> regs (2-deep; issue order A then B preserved)
        if (j + 2 < ITERS) {
            const int j2 = j + 2;
            bset = *(const float4*)(Xb + (size_t)(j2 >> 4) * (BN * D_DIM) + (j2 & 15) * 32);
        }
        __builtin_amdgcn_sched_barrier(0);
        // compute(j)
        const char* Ab = smem + (j & 1) * 16384;
        const char* Bb = smem + 32768 + (j & 1) * 4096;
        half8 af[4];
#pragma unroll
        for (int mi = 0; mi < 4; ++mi)
            af[mi] = *(const half8*)(Ab + a_off[mi]);
        const half8 bf0 = *(const half8*)(Bb + b_off[0]);
        const half8 bf1 = *(const half8*)(Bb + b_off[1]);
#pragma unroll
        for (int mi = 0; mi < 4; ++mi) {
            acc[mi][0] = __builtin_amdgcn_mfma_f32_16x16x32_f16(af[mi], bf0, acc[mi][0], 0, 0, 0);
            acc[mi][1] = __builtin_amdgcn_mfma_f32_16x16x32_f16(af[mi], bf1, acc[mi][1], 0, 0, 0);
        }
        // nt epilogue: 4 slabs of 16 cols; dump (swizzled) -> top-6 scan
        if ((j & 15) == 15) {
            const int colbase = bc * NR + (j >> 4) * BN;
#pragma unroll
            for (int s = 0; s < 4; ++s) {
                if (wn == (s >> 1)) {
                    const int ni = s & 1;
#pragma unroll
                    for (int mi = 0; mi < 4; ++mi)
#pragma unroll
                        for (int r = 0; r < 4; ++r) {
                            const int rr = wm * 64 + mi * 16 + (lane >> 4) * 4 + r;
                            Cs[rr * 16 + ((lane & 15) ^ ((rr >> 1) & 15))] = acc[mi][ni][r];
                        }
                }
                asm volatile("s_waitcnt lgkmcnt(0)" ::: "memory");
                __builtin_amdgcn_s_barrier();
                if (tid < 256) {
                    const int r = tid;
                    const int base = colbase + s * 16;
                    for (int c = 0; c < 16; ++c) {
                        const float v = Cs[r * 16 + (c ^ ((r >> 1) & 15))];
                        const int id = base + c;
                        if (v > topv[CAND - 1] ||
                            (v == topv[CAND - 1] && id < topi[CAND - 1])) {
                            topv[CAND - 1] = v; topi[CAND - 1] = id;
#pragma unroll
                            for (int t = CAND - 1; t > 0; --t) {
                                const bool gt = topv[t] > topv[t - 1] ||
                                    (topv[t] == topv[t - 1] && topi[t] < topi[t - 1]);
                                if (gt) {
                                    const float tv = topv[t]; topv[t] = topv[t - 1]; topv[t - 1] = tv;
                                    const int   ti = topi[t]; topi[t] = topi[t - 1]; topi[t - 1] = ti;
                                }
                            }
                        }
                    }
                }
                asm volatile("s_waitcnt lgkmcnt(0)" ::: "memory");
                __builtin_amdgcn_s_barrier();
            }
#pragma unroll
            for (int mi = 0; mi < 4; ++mi) { acc[mi][0] = (f32x4)0.0f; acc[mi][1] = (f32x4)0.0f; }
        }
    };

    for (int jj = 0; jj < ITERS; jj += 2) {
        step(jj,     bE);
        step(jj + 1, bO);
    }

    if (tid < 256) {
        const size_t base = ((size_t)(row0 + tid) * CHUNKS + bc) * CAND;
#pragma unroll
        for (int j = 0; j < CAND; ++j) {
            cand_v[base + j] = topv[j];
            cand_i[base + j] = topi[j];
        }
    }
}

// --------------------------------------------------------------------- p2 --
// One block per row. Pivot = 24th-largest chunk-head under (v desc, idx asc)
// => pool {e >= pivot} provably contains the f16-top-24 => true top-10.
// Exact fp32 rescore of the pool from original Q,X; deterministic rank.
__global__ __launch_bounds__(256)
void faiss_p2(const float* __restrict__ cand_v, const int* __restrict__ cand_i,
              const float* __restrict__ Q, const float* __restrict__ X,
              int* __restrict__ out)
{
    __shared__ float vs[NCAND];
    __shared__ int   is[NCAND];
    __shared__ float qs[D_DIM];
    __shared__ int   Sidx[NCAND];
    __shared__ float Sval[NCAND];
    __shared__ int   scount;
    __shared__ float pivV;
    __shared__ int   pivI;

    const int row = blockIdx.x, tid = threadIdx.x;

    for (int i = tid; i < NCAND; i += 256) {
        vs[i] = cand_v[(size_t)row * NCAND + i];
        is[i] = cand_i[(size_t)row * NCAND + i];
    }
    if (tid < 128)
        ((float4*)qs)[tid] = ((const float4*)(Q + (size_t)row * D_DIM))[tid];
    if (tid == 0) scount = 0;
    __syncthreads();

    // rank the 256 chunk-heads; thread with rank 23 publishes the pivot
    {
        const float h = vs[tid * CAND];
        const int  hid = is[tid * CAND];
        int r = 0;
        for (int j = 0; j < CHUNKS; ++j) {
            const float vj = vs[j * CAND];
            r += (vj > h) || (vj == h && is[j * CAND] < hid);
        }
        if (r == 23) { pivV = h; pivI = hid; }
    }
    __syncthreads();

    // filter: keep everything >= pivot under the total order
    const float pv = pivV; const int pi = pivI;
    for (int i = tid; i < NCAND; i += 256) {
        const float v = vs[i]; const int id = is[i];
        if (v > pv || (v == pv && id <= pi)) {
            const int p = atomicAdd(&scount, 1);
            Sidx[p] = id;
        }
    }
    __syncthreads();
    const int nS = scount;

    // exact fp32 rescore: one wave per candidate, deterministic reduce
    const int wv = tid >> 6, ln = tid & 63;
    for (int si = wv; si < nS; si += 4) {
        const float* xr = X + (size_t)Sidx[si] * D_DIM + ln * 8;
        const float4 xa = *(const float4*)(xr);
        const float4 xb = *(const float4*)(xr + 4);
        const float* qp = qs + ln * 8;
        float s = 0.0f;
        s = fmaf(qp[0], xa.x, s); s = fmaf(qp[1], xa.y, s);
        s = fmaf(qp[2], xa.z, s); s = fmaf(qp[3], xa.w, s);
        s = fmaf(qp[4], xb.x, s); s = fmaf(qp[5], xb.y, s);
        s = fmaf(qp[6], xb.z, s); s = fmaf(qp[7], xb.w, s);
#pragma unroll
        for (int off = 32; off > 0; off >>= 1)
            s += __shfl_down(s, off);
        if (ln == 0) Sval[si] = s;
    }
    __syncthreads();

    // final deterministic rank-select among the pool
    for (int i = tid; i < nS; i += 256) {
        const float v = Sval[i]; const int id = Sidx[i];
        int r = 0;
        for (int j = 0; j < nS; ++j) {
            const float vj = Sval[j];
            r += (vj > v) || (vj == v && Sidx[j] < id);
        }
        if (r < TOPK) out[row * TOPK + r] = id;
    }
}

// ----------------------------------------------------------------- launch --
extern "C" void kernel_launch(void* const* d_in, const int* in_sizes, int n_in,
                              void* d_out, int out_size, void* d_ws, size_t ws_size,
                              hipStream_t stream)
{
    (void)in_sizes; (void)n_in; (void)out_size; (void)ws_size;
    const float* Q = (const float*)d_in[0];
    const float* X = (const float*)d_in[1];
    int* out = (int*)d_out;

    char* ws = (char*)d_ws;
    float*    cand_v = (float*)ws;                                   // 3.15 MB
    int*      cand_i = (int*)(ws + (size_t)B_Q * NCAND * 4);         // 3.15 MB
    _Float16* Qsw    = (_Float16*)(ws + (size_t)B_Q * NCAND * 8);    // 512 KB

    qprep<<<dim3(B_Q * D_DIM / 8 / 256), dim3(256), 0, stream>>>(Q, Qsw);
    faiss_p1<<<dim3(512), dim3(512), 0, stream>>>(Qsw, X, cand_v, cand_i);
    faiss_p2<<<dim3(B_Q), dim3(256), 0, stream>>>(cand_v, cand_i, Q, X, out);
}